// Round 8
// baseline (204.478 us; speedup 1.0000x reference)
//
#include <hip/hip_runtime.h>
#include <cstdint>
#include <cstddef>

#define SEQL   2048
#define DMODEL 1024
#define NHEADS 16
#define DHEAD  64
#define MROWS  4096   // BATCH * SEQ

typedef __attribute__((ext_vector_type(8))) short short8;   // 8 bf16 (4 VGPRs)
typedef __attribute__((ext_vector_type(4))) float f32x4;    // MFMA 16x16 C/D

__device__ __forceinline__ unsigned short f2bf(float x) {
  unsigned int u = __float_as_uint(x);
  u += 0x7fffu + ((u >> 16) & 1u);   // round-to-nearest-even
  return (unsigned short)(u >> 16);
}
__device__ __forceinline__ float bf2f(unsigned short u) {
  return __uint_as_float(((unsigned int)u) << 16);
}
// load 8 contiguous fp32, round to 8 bf16
__device__ __forceinline__ short8 cvt8(const float* __restrict__ p) {
  const float4 lo = *(const float4*)p;
  const float4 hi = *(const float4*)(p + 4);
  short8 v;
  v[0] = (short)f2bf(lo.x); v[1] = (short)f2bf(lo.y);
  v[2] = (short)f2bf(lo.z); v[3] = (short)f2bf(lo.w);
  v[4] = (short)f2bf(hi.x); v[5] = (short)f2bf(hi.y);
  v[6] = (short)f2bf(hi.z); v[7] = (short)f2bf(hi.w);
  return v;
}
// async global->LDS, 16B per lane; lds base must be wave-uniform
__device__ __forceinline__ void gload_lds16(const unsigned short* g, unsigned short* l) {
  __builtin_amdgcn_global_load_lds(
      (const __attribute__((address_space(1))) unsigned int*)g,
      (__attribute__((address_space(3))) unsigned int*)l, 16, 0, 0);
}

// ---------------------------------------------------------------------------
// One-shot fp32 -> bf16 conversion of x and the four weight matrices.
// ---------------------------------------------------------------------------
__global__ __launch_bounds__(256) void cvt_bf16(
    const float* __restrict__ x,  const float* __restrict__ wq,
    const float* __restrict__ wk, const float* __restrict__ wv,
    const float* __restrict__ wo,
    unsigned short* __restrict__ xb,  unsigned short* __restrict__ wqb,
    unsigned short* __restrict__ wkb, unsigned short* __restrict__ wvb,
    unsigned short* __restrict__ wob) {
  const int y = blockIdx.y;
  const float* src; unsigned short* dst;
  if (y < 4)       { src = x + ((size_t)y << 20); dst = xb + ((size_t)y << 20); }
  else if (y == 4) { src = wq; dst = wqb; }
  else if (y == 5) { src = wk; dst = wkb; }
  else if (y == 6) { src = wv; dst = wvb; }
  else             { src = wo; dst = wob; }
  const size_t i = ((size_t)blockIdx.x * 256 + threadIdx.x) * 8;
  *(short8*)(dst + i) = cvt8(src + i);
}

// ---------------------------------------------------------------------------
// QKV projection R18: 256x256 tile, 8 waves, BK=32, TRIPLE-buffered linear
// LDS, counted vmcnt (T3+T4, never 0 in-loop), raw s_barrier, setprio around
// MFMA clusters (T5). Staging runs 2 K-tiles ahead; vmcnt(4) at tile end
// guarantees tile t+1's 4 stage-ops (issued during t-1) have landed while
// tile t+2's 4 stay in flight. LDS 96KB -> 1 block/CU, 2 waves/SIMD.
// Thread map row=tid>>2, col=(tid&3)*8 makes linear [row][32] LDS exactly
// wave-uniform-base + lane*16B (global_load_lds-compatible, no swizzle).
// z=0 -> Q bf16; z=1 -> K bf16; z=2 -> V transposed into Vt.
// Math/accumulation order identical to the proven 128x128 kernel.
// ---------------------------------------------------------------------------
__global__ __launch_bounds__(512, 2) void gemm_qkv(
    const unsigned short* __restrict__ A,
    const unsigned short* __restrict__ W0, const unsigned short* __restrict__ W1,
    const unsigned short* __restrict__ W2,
    unsigned short* __restrict__ C0, unsigned short* __restrict__ C1,
    unsigned short* __restrict__ Vt) {
  const unsigned short* W;
  if (blockIdx.z == 0)      W = W0;
  else if (blockIdx.z == 1) W = W1;
  else                      W = W2;

  __shared__ __attribute__((aligned(16))) unsigned short As[3][8192];  // 3 x 16 KB
  __shared__ __attribute__((aligned(16))) unsigned short Bs[3][8192];  // 3 x 16 KB

  const int tid = threadIdx.x;
  const int wid = tid >> 6, lane = tid & 63;
  const int l15 = lane & 15, quad = lane >> 4;
  const int wm2 = wid >> 2;          // 0..1: wave's 128-row half
  const int wn4 = wid & 3;           // 0..3: wave's 64-col quarter
  const int m0 = blockIdx.y * 256, n0 = blockIdx.x * 256;

  // staging: thread covers k-tile row tid>>2 (+s*128), cols (tid&3)*8..+7
  const unsigned short* agp = A + (size_t)(m0 + (tid >> 2)) * DMODEL + (tid & 3) * 8;
  const unsigned short* bgp = W + (size_t)(n0 + (tid >> 2)) * DMODEL + (tid & 3) * 8;
  const int ldofs = wid << 9;        // wave-uniform LDS base (shorts)

#define STAGE_A(buf, kt)                                                      \
  {                                                                           \
    gload_lds16(agp + (size_t)(kt) * 32, &As[buf][ldofs]);                    \
    gload_lds16(agp + (size_t)128 * DMODEL + (size_t)(kt) * 32,               \
                &As[buf][4096 + ldofs]);                                      \
  }
#define STAGE_B(buf, kt)                                                      \
  {                                                                           \
    gload_lds16(bgp + (size_t)(kt) * 32, &Bs[buf][ldofs]);                    \
    gload_lds16(bgp + (size_t)128 * DMODEL + (size_t)(kt) * 32,               \
                &Bs[buf][4096 + ldofs]);                                      \
  }

  // fragment read offsets (shorts): row*32 + quad*8, rows per mf/nf step = 16
  const int arow = (wm2 * 128 + l15) * 32 + quad * 8;    // + mf*512
  const int brow = (wn4 * 64 + l15) * 32 + quad * 8;     // + nf*512

  f32x4 acc[8][4] = {};

  // prologue: stage tiles 0 and 1; ensure tile 0 landed (vmcnt 8 -> 4)
  STAGE_A(0, 0); STAGE_B(0, 0);
  STAGE_A(1, 1); STAGE_B(1, 1);
  asm volatile("s_waitcnt vmcnt(4)" ::: "memory");
  __builtin_amdgcn_s_barrier();

  int cur = 0, nxt = 2;
  const int NT = DMODEL / 32;   // 32 k-tiles
#pragma unroll 1
  for (int t = 0; t < NT; ++t) {
    const unsigned short* ab = As[cur];
    const unsigned short* bb = Bs[cur];

    // ---- phase 1: A frags + B frags 0,1; stage A(t+2); 16 MFMA ----
    short8 a0 = *(const short8*)(ab + arow);
    short8 a1 = *(const short8*)(ab + arow + 512);
    short8 a2 = *(const short8*)(ab + arow + 1024);
    short8 a3 = *(const short8*)(ab + arow + 1536);
    short8 a4 = *(const short8*)(ab + arow + 2048);
    short8 a5 = *(const short8*)(ab + arow + 2560);
    short8 a6 = *(const short8*)(ab + arow + 3072);
    short8 a7 = *(const short8*)(ab + arow + 3584);
    short8 b0 = *(const short8*)(bb + brow);
    short8 b1 = *(const short8*)(bb + brow + 512);
    if (t + 2 < NT) STAGE_A(nxt, t + 2);
    __builtin_amdgcn_s_barrier();
    asm volatile("s_waitcnt lgkmcnt(0)" ::: "memory");
    __builtin_amdgcn_sched_barrier(0);
    __builtin_amdgcn_s_setprio(1);
    acc[0][0] = __builtin_amdgcn_mfma_f32_16x16x32_bf16(a0, b0, acc[0][0], 0, 0, 0);
    acc[0][1] = __builtin_amdgcn_mfma_f32_16x16x32_bf16(a0, b1, acc[0][1], 0, 0, 0);
    acc[1][0] = __builtin_amdgcn_mfma_f32_16x16x32_bf16(a1, b0, acc[1][0], 0, 0, 0);
    acc[1][1] = __builtin_amdgcn_mfma_f32_16x16x32_bf16(a1, b1, acc[1][1], 0, 0, 0);
    acc[2][0] = __builtin_amdgcn_mfma_f32_16x16x32_bf16(a2, b0, acc[2][0], 0, 0, 0);
    acc[2][1] = __builtin_amdgcn_mfma_f32_16x16x32_bf16(a2, b1, acc[2][1], 0, 0, 0);
    acc[3][0] = __builtin_amdgcn_mfma_f32_16x16x32_bf16(a3, b0, acc[3][0], 0, 0, 0);
    acc[3][1] = __builtin_amdgcn_mfma_f32_16x16x32_bf16(a3, b1, acc[3][1], 0, 0, 0);
    acc[4][0] = __builtin_amdgcn_mfma_f32_16x16x32_bf16(a4, b0, acc[4][0], 0, 0, 0);
    acc[4][1] = __builtin_amdgcn_mfma_f32_16x16x32_bf16(a4, b1, acc[4][1], 0, 0, 0);
    acc[5][0] = __builtin_amdgcn_mfma_f32_16x16x32_bf16(a5, b0, acc[5][0], 0, 0, 0);
    acc[5][1] = __builtin_amdgcn_mfma_f32_16x16x32_bf16(a5, b1, acc[5][1], 0, 0, 0);
    acc[6][0] = __builtin_amdgcn_mfma_f32_16x16x32_bf16(a6, b0, acc[6][0], 0, 0, 0);
    acc[6][1] = __builtin_amdgcn_mfma_f32_16x16x32_bf16(a6, b1, acc[6][1], 0, 0, 0);
    acc[7][0] = __builtin_amdgcn_mfma_f32_16x16x32_bf16(a7, b0, acc[7][0], 0, 0, 0);
    acc[7][1] = __builtin_amdgcn_mfma_f32_16x16x32_bf16(a7, b1, acc[7][1], 0, 0, 0);
    __builtin_amdgcn_s_setprio(0);
    __builtin_amdgcn_s_barrier();

    // ---- phase 2: B frags 2,3; stage B(t+2); 16 MFMA; counted vmcnt ----
    short8 b2 = *(const short8*)(bb + brow + 1024);
    short8 b3 = *(const short8*)(bb + brow + 1536);
    if (t + 2 < NT) STAGE_B(nxt, t + 2);
    __builtin_amdgcn_s_barrier();
    asm volatile("s_waitcnt lgkmcnt(0)" ::: "memory");
    __builtin_amdgcn_sched_barrier(0);
    __builtin_amdgcn_s_setprio(1);
    acc[0][2] = __builtin_amdgcn_mfma_f32_16x16x32_bf16(a0, b2, acc[0][2], 0, 0, 0);
    acc[0][3] = __builtin_amdgcn_mfma_f32_16x16x32_bf16(a0, b3, acc[0][3], 0, 0, 0);
    acc[1][2] = __builtin_amdgcn_mfma_f32_16x16x32_bf16(a1, b2, acc[1][2], 0, 0, 0);
    acc[1][3] = __builtin_amdgcn_mfma_f32_16x16x32_bf16(a1, b3, acc[1][3], 0, 0, 0);
    acc[2][2] = __builtin_amdgcn_mfma_f32_16x16x32_bf16(a2, b2, acc[2][2], 0, 0, 0);
    acc[2][3] = __builtin_amdgcn_mfma_f32_16x16x32_bf16(a2, b3, acc[2][3], 0, 0, 0);
    acc[3][2] = __builtin_amdgcn_mfma_f32_16x16x32_bf16(a3, b2, acc[3][2], 0, 0, 0);
    acc[3][3] = __builtin_amdgcn_mfma_f32_16x16x32_bf16(a3, b3, acc[3][3], 0, 0, 0);
    acc[4][2] = __builtin_amdgcn_mfma_f32_16x16x32_bf16(a4, b2, acc[4][2], 0, 0, 0);
    acc[4][3] = __builtin_amdgcn_mfma_f32_16x16x32_bf16(a4, b3, acc[4][3], 0, 0, 0);
    acc[5][2] = __builtin_amdgcn_mfma_f32_16x16x32_bf16(a5, b2, acc[5][2], 0, 0, 0);
    acc[5][3] = __builtin_amdgcn_mfma_f32_16x16x32_bf16(a5, b3, acc[5][3], 0, 0, 0);
    acc[6][2] = __builtin_amdgcn_mfma_f32_16x16x32_bf16(a6, b2, acc[6][2], 0, 0, 0);
    acc[6][3] = __builtin_amdgcn_mfma_f32_16x16x32_bf16(a6, b3, acc[6][3], 0, 0, 0);
    acc[7][2] = __builtin_amdgcn_mfma_f32_16x16x32_bf16(a7, b2, acc[7][2], 0, 0, 0);
    acc[7][3] = __builtin_amdgcn_mfma_f32_16x16x32_bf16(a7, b3, acc[7][3], 0, 0, 0);
    __builtin_amdgcn_s_setprio(0);
    // counted drain: all but the 4 youngest (tile t+2's) must have landed
    // -> tile t+1's staging is complete before the next iteration reads it.
    asm volatile("s_waitcnt vmcnt(4)" ::: "memory");
    __builtin_amdgcn_s_barrier();

    cur = (cur == 2) ? 0 : cur + 1;
    nxt = (nxt == 2) ? 0 : nxt + 1;
  }
#undef STAGE_A
#undef STAGE_B

  // ---- epilogue ----
  if (blockIdx.z != 2) {
    unsigned short* C = (blockIdx.z == 0) ? C0 : C1;
#pragma unroll
    for (int mf = 0; mf < 8; ++mf)
#pragma unroll
      for (int nf = 0; nf < 4; ++nf) {
        const int row = m0 + wm2 * 128 + mf * 16 + quad * 4;
        const int col = n0 + wn4 * 64 + nf * 16 + l15;
#pragma unroll
        for (int r = 0; r < 4; ++r)
          C[(size_t)(row + r) * DMODEL + col] = f2bf(acc[mf][nf][r]);
      }
  } else {
    // V transposed write: 4 consecutive s-values per 8B store
#pragma unroll
    for (int mf = 0; mf < 8; ++mf) {
      const int srow = m0 + wm2 * 128 + mf * 16 + quad * 4;  // b*SEQL + s
      const int bq = srow >> 11, s = srow & (SEQL - 1);
#pragma unroll
      for (int nf = 0; nf < 4; ++nf) {
        const int col = n0 + wn4 * 64 + nf * 16 + l15;       // h*64 + d
        ushort4 v;
        v.x = f2bf(acc[mf][nf][0]); v.y = f2bf(acc[mf][nf][1]);
        v.z = f2bf(acc[mf][nf][2]); v.w = f2bf(acc[mf][nf][3]);
        *(ushort4*)(Vt + ((size_t)(bq * DMODEL + col)) * SEQL + s) = v;
      }
    }
  }
}

// ---------------------------------------------------------------------------
// Output projection: A bf16 [M][K], W bf16 [N][K], C fp32 [M][N]
// (proven m97-style 128x128 kernel, unchanged)
// ---------------------------------------------------------------------------
__global__ __launch_bounds__(256) void gemm_out(
    const unsigned short* __restrict__ A,
    const unsigned short* __restrict__ W,
    float* __restrict__ C,
    int Mda, int Nda, int Kda) {
  __shared__ __attribute__((aligned(16))) unsigned short As[128 * 32];
  __shared__ __attribute__((aligned(16))) unsigned short Bs[128 * 32];

  const int t = threadIdx.x;
  const int m0 = blockIdx.y * 128, n0 = blockIdx.x * 128;
  const int w = t >> 6, lane = t & 63;
  const int l15 = lane & 15, quad = lane >> 4;
  const int wm = (w >> 1) * 64, wn = (w & 1) * 64;

  const int r1 = t >> 2,         c1 = (t & 3) * 8;
  const int r2 = (t + 256) >> 2, c2 = (t & 3) * 8;
  unsigned short* asd1 = As + (size_t)(w << 6) * 8;
  unsigned short* asd2 = As + (size_t)(256 + (w << 6)) * 8;
  unsigned short* bsd1 = Bs + (size_t)(w << 6) * 8;
  unsigned short* bsd2 = Bs + (size_t)(256 + (w << 6)) * 8;

  f32x4 acc[4][4] = {};

  for (int k0 = 0; k0 < Kda; k0 += 32) {
    __syncthreads();
    gload_lds16(A + (size_t)(m0 + r1) * Kda + k0 + c1, asd1);
    gload_lds16(A + (size_t)(m0 + r2) * Kda + k0 + c2, asd2);
    gload_lds16(W + (size_t)(n0 + r1) * Kda + k0 + c1, bsd1);
    gload_lds16(W + (size_t)(n0 + r2) * Kda + k0 + c2, bsd2);
    __syncthreads();

    short8 af[4], bfr[4];
#pragma unroll
    for (int i = 0; i < 4; ++i)
      af[i] = *(const short8*)(&As[(wm + i * 16 + l15) * 32 + quad * 8]);
#pragma unroll
    for (int j = 0; j < 4; ++j)
      bfr[j] = *(const short8*)(&Bs[(wn + j * 16 + l15) * 32 + quad * 8]);
#pragma unroll
    for (int i = 0; i < 4; ++i)
#pragma unroll
      for (int j = 0; j < 4; ++j)
        acc[i][j] = __builtin_amdgcn_mfma_f32_16x16x32_bf16(af[i], bfr[j], acc[i][j], 0, 0, 0);
  }

#pragma unroll
  for (int i = 0; i < 4; ++i)
#pragma unroll
    for (int j = 0; j < 4; ++j)
#pragma unroll
      for (int r = 0; r < 4; ++r) {
        int row = m0 + wm + i * 16 + quad * 4 + r;
        int col = n0 + wn + j * 16 + l15;
        C[(size_t)row * Nda + col] = acc[i][j][r];
      }
}

// ---------------------------------------------------------------------------
// In-place RoPE on bf16 Q and K flat [M][1024].  Table-in-LDS (R17).
// ---------------------------------------------------------------------------
__global__ __launch_bounds__(256) void rope_inplace(unsigned short* __restrict__ Q,
                                                    unsigned short* __restrict__ K,
                                                    const int* __restrict__ pos_arr) {
  __shared__ float cs[32], sn[32];
  const int row = blockIdx.x;            // b*SEQ + s
  const int s = row & (SEQL - 1);
  const int t = threadIdx.x;
  if (t < 32) {
    const float pos = (float)pos_arr[s];
    // log2(10000)/32 = 0.4152410118609203
    const float inv = exp2f((float)t * -0.4152410118609203f);
    const float ang = pos * inv;
    float ss, cc;
    sincosf(ang, &ss, &cc);
    cs[t] = cc; sn[t] = ss;
  }
  __syncthreads();

  // thread t handles head h = t>>4, pairs i0 = (t&15)*2 and i0+1 (4 shorts)
  const int i0 = (t & 15) * 2;
  const size_t base = (size_t)row * DMODEL + (size_t)(t >> 4) * DHEAD + (size_t)i0 * 2;
  const float c0 = cs[i0], s0 = sn[i0];
  const float c1 = cs[i0 + 1], s1 = sn[i0 + 1];

  ushort4 q = *(const ushort4*)(Q + base);
  ushort4 k = *(const ushort4*)(K + base);
  ushort4 r;
  float e, o;
  e = bf2f(q.x); o = bf2f(q.y);
  r.x = f2bf((e * c0 - o * s0) * 0.125f);
  r.y = f2bf((e * s0 + o * c0) * 0.125f);
  e = bf2f(q.z); o = bf2f(q.w);
  r.z = f2bf((e * c1 - o * s1) * 0.125f);
  r.w = f2bf((e * s1 + o * c1) * 0.125f);
  *(ushort4*)(Q + base) = r;

  e = bf2f(k.x); o = bf2f(k.y);
  r.x = f2bf(e * c0 - o * s0);
  r.y = f2bf(e * s0 + o * c0);
  e = bf2f(k.z); o = bf2f(k.w);
  r.z = f2bf(e * c1 - o * s1);
  r.w = f2bf(e * s1 + o * c1);
  *(ushort4*)(K + base) = r;
}

// ---------------------------------------------------------------------------
// Causal attention — PROVEN R0 version (46.8us, VGPR 44, no spills).
// ---------------------------------------------------------------------------
__global__ __launch_bounds__(256, 2) void attn_kernel(const unsigned short* __restrict__ Kf,
                                                      const unsigned short* __restrict__ Vt,
                                                      unsigned short* __restrict__ Qio) {
  __shared__ __attribute__((aligned(16))) unsigned short Ks[4096];  // 8 KB: kv64 x d64
  __shared__ __attribute__((aligned(16))) unsigned short Vs[4096];  // 8 KB: d64 x kv64

  const int id = blockIdx.x;                    // id = grp*128 + qpair*8 + xcd
  const int bh = ((id >> 7) << 3) | (id & 7);   // grp*8 + xcd (L2 locality)
  const int qpair = (id >> 3) & 15;             // 0..15
  const int b = bh >> 4, h = bh & 15;
  const int w = threadIdx.x >> 6;
  const int lane = threadIdx.x & 63;
  const int l15 = lane & 15, quad = lane >> 4;

  // staging source addresses (lane-permuted so LDS slot = fragment layout)
  const int g = (w << 6) | lane;
  const int ktau = g >> 7, kseg = (g >> 4) & 7, km = g & 15;
  const int kvl = 8 * (km >> 2) + (km & 3) + 4 * ktau;
  const unsigned short* kstage = Kf + ((size_t)(b * SEQL + kvl)) * DMODEL + h * DHEAD + kseg * 8;
  const int vdb = (g >> 6) & 3, vq = (g >> 4) & 3, vm = g & 15;
  const unsigned short* vstage = Vt + ((size_t)(bh * DHEAD + vdb * 16 + vm)) * SEQL + vq * 8;
  unsigned short* kdst0 = Ks + (size_t)(w << 6) * 8;          // kv 0..31 half
  unsigned short* kdst1 = Ks + 2048 + (size_t)(w << 6) * 8;   // kv 32..63 half
  unsigned short* vdst0 = Vs + (size_t)(w << 6) * 8;
  unsigned short* vdst1 = Vs + 2048 + (size_t)(w << 6) * 8;

  // fragment read offset (shorts) within a 2048-short half
  const int rs = (l15 + (quad << 4)) << 3;

#pragma unroll 1
  for (int phase = 0; phase < 2; ++phase) {
    const int qblk = (phase == 0) ? qpair : 31 - qpair;
    const int qw = qblk * 64 + w * 16;
    const int qrow = qw + l15;

    // Q B-frag: n=l15 (q), k=8*quad+j (d)
    const unsigned short* qp = Qio + ((size_t)(b * SEQL + qrow)) * DMODEL + h * DHEAD + quad * 8;
    const short8 bq0 = *(const short8*)(qp);
    const short8 bq1 = *(const short8*)(qp + 32);

    f32x4 oa0 = {0.f, 0.f, 0.f, 0.f}, oa1 = oa0, oa2 = oa0, oa3 = oa0;
    float lp = 0.f;

    const int trips = qblk + 1;   // kv64 tiles; block-uniform
    for (int t = 0; t < trips; ++t) {
      const int kv0 = t * 64;
      __syncthreads();   // all waves done reading previous tile
      gload_lds16(kstage + (size_t)kv0 * DMODEL, kdst0);
      gload_lds16(kstage + (size_t)(kv0 + 32) * DMODEL, kdst1);
      gload_lds16(vstage + kv0, vdst0);
      gload_lds16(vstage + kv0 + 32, vdst1);
      __syncthreads();   // staged data visible

      // QK^T: 4 score accumulators (kv groups +0, +4, +32, +36)
      const short8 ak10 = *(const short8*)(Ks + rs);
      const short8 ak11 = *(const short8*)(Ks + rs + 512);
      const short8 ak20 = *(const short8*)(Ks + rs + 1024);
      const short8 ak21 = *(const short8*)(Ks + rs + 1536);
      const short8 ak30 = *(const short8*)(Ks + 2048 + rs);
      const short8 ak31 = *(const short8*)(Ks + 2048 + rs + 512);
      const short8 ak40 = *(const short8*)(Ks + 2048 + rs + 1024);
      const short8 ak41 = *(const short8*)(Ks + 2048 + rs + 1536);
      f32x4 z = {0.f, 0.f, 0.f, 0.f};
      f32x4 s1 = __builtin_amdgcn_mfma_f32_16x16x32_bf16(ak10, bq0, z, 0, 0, 0);
      s1 = __builtin_amdgcn_mfma_f32_16x16x32_bf16(ak11, bq1, s1, 0, 0, 0);
      f32x4 s2 = __builtin_amdgcn_mfma_f32_16x16x32_bf16(ak20, bq0, z, 0, 0, 0);
      s2 = __builtin_amdgcn_mfma_f32_16x16x32_bf16(ak21, bq1, s2, 0, 0, 0);
      f32x4 s3 = __builtin_amdgcn_mfma_f32_16x16x32_bf16(ak30, bq0, z, 0, 0, 0);
      s3 = __builtin_amdgcn_mfma_f32_16x16x32_bf16(ak31, bq1, s3, 0, 0, 0);
      f32x4 s4 = __builtin_amdgcn_mfma_f32_16x16x32_bf16(ak40, bq0, z, 0, 0, 0);
      s4 = __builtin_amdgcn_mfma_f32_16x16x32_bf16(ak41, bq1, s4, 0, 0, 0);

      // exp (+causal mask on the last trip per wave) -> PV B-operands
      short8 bp0, bp1;
      if (kv0 + 63 <= qw) {   // wave-uniform fast path: no masking needed
#pragma unroll
        for (int r = 0; r < 4; ++r) {
          const float p1 = __expf(s1[r]);
          const float p2 = __expf(s2[r]);
          const float p3 = __expf(s3[r]);
          const float p4 = __expf(s4[r]);
          lp += (p1 + p2) + (p3 + p4);
          bp0[r]     = (short)f2bf(p1);
          bp0[4 + r] = (short)f2bf(p2);
          bp1[r]     = (short)f2bf(p3);
          bp1[4 + r] = (short)f2bf(p4);
        }
      } else {
#pragma unroll
        for (int r = 0; r < 4; ++r) {
          const int kv1 = kv0 + 8 * quad + r;
          const float p1 = (kv1 > qrow)      ? 0.f : __expf(s1[r]);
          const float p2 = (kv1 + 4 > qrow)  ? 0.f : __expf(s2[r]);
          const float p3 = (kv1 + 32 > qrow) ? 0.f : __expf(s3[r]);
          const float p4 = (kv1 + 36 > qrow) ? 0.f : __expf(s4[r]);
          lp += (p1 + p2) + (p3 + p4);
          bp0[r]     = (short)f2bf(p1);
          bp0[4 + r] = (short)f2bf(p2);
          bp1[r]     = (short)f2bf(p3);
          bp1[4 + r] = (short)f2bf(p4);
        }
      }

      // PV: A = V^T frags (d-block x kv-half), B = bp
      const short8 av0l = *(const short8*)(Vs + rs);
      const short8 av1l = *(const short8*)(Vs + rs + 512);
      const short8 av2l = *(const short8*)(Vs + rs + 1024);
      const short8 av3l = *(const short8*)(Vs + rs + 1536);
      const short8 av0h = *(const short8*)(Vs + 2048 + rs);
      const short8 av1h = *(const short8*)(Vs + 2048 + rs + 512);
      const short8 av2h = *(const short8*)(Vs + 2048 + rs + 1024);
      const short8 av3h = *(const short8*)(Vs + 2048 + rs + 1536);
      oa0 = __builtin_amdgcn_mfma_f32_16x16x32_bf16(av0l, bp0, oa0, 0, 0, 0);
      oa1 = __builtin_amdgcn_mfma_f32_16x16x32_bf16(av1l, bp0, oa1, 0, 0, 0);
      oa2 = __builtin_amdgcn_mfma_f32_16x16x32_bf16(av2l, bp0, oa2, 0, 0, 0);
      oa3 = __builtin_amdgcn_mfma_f32_16x16x32_bf16(av3l, bp0, oa3, 0, 0, 0);
      oa0 = __builtin_amdgcn_mfma_f32_16x16x32_bf16(av0h, bp1, oa0, 0, 0, 0);
      oa1 = __builtin_amdgcn_mfma_f32_16x16x32_bf16(av1h, bp1, oa1, 0, 0, 0);
      oa2 = __builtin_amdgcn_mfma_f32_16x16x32_bf16(av2h, bp1, oa2, 0, 0, 0);
      oa3 = __builtin_amdgcn_mfma_f32_16x16x32_bf16(av3h, bp1, oa3, 0, 0, 0);
    }

    // reduce row sum across the 4 quads holding this q's kv slices
    lp += __shfl_xor(lp, 16);
    lp += __shfl_xor(lp, 32);
    const float il = 1.f / lp;

    // O^T: lane holds q=l15's d = db*16 + 4*quad + r  -> 4x ushort4 stores
    unsigned short* ob = Qio + ((size_t)(b * SEQL + qrow)) * DMODEL + h * DHEAD + quad * 4;
    {
      ushort4 v;
      v.x = f2bf(oa0[0] * il); v.y = f2bf(oa0[1] * il);
      v.z = f2bf(oa0[2] * il); v.w = f2bf(oa0[3] * il);
      *(ushort4*)(ob) = v;
      v.x = f2bf(oa1[0] * il); v.y = f2bf(oa1[1] * il);
      v.z = f2bf(oa1[2] * il); v.w = f2bf(oa1[3] * il);
      *(ushort4*)(ob + 16) = v;
      v.x = f2bf(oa2[0] * il); v.y = f2bf(oa2[1] * il);
      v.z = f2bf(oa2[2] * il); v.w = f2bf(oa2[3] * il);
      *(ushort4*)(ob + 32) = v;
      v.x = f2bf(oa3[0] * il); v.y = f2bf(oa3[1] * il);
      v.z = f2bf(oa3[2] * il); v.w = f2bf(oa3[3] * il);
      *(ushort4*)(ob + 48) = v;
    }
  }
}

// ---------------------------------------------------------------------------
extern "C" void kernel_launch(void* const* d_in, const int* in_sizes, int n_in,
                              void* d_out, int out_size, void* d_ws, size_t ws_size,
                              hipStream_t stream) {
  (void)in_sizes; (void)n_in; (void)out_size; (void)ws_size;
  const float* x  = (const float*)d_in[0];
  const int* tpos = (const int*)d_in[1];
  const float* Wq = (const float*)d_in[2];
  const float* Wk = (const float*)d_in[3];
  const float* Wv = (const float*)d_in[4];
  const float* Wo = (const float*)d_in[5];
  float* out      = (float*)d_out;

  char* ws = (char*)d_ws;
  const size_t MB = 1024 * 1024;
  unsigned short* Qf  = (unsigned short*)(ws);            // 8 MB
  unsigned short* Kf  = (unsigned short*)(ws + 8 * MB);   // 8 MB
  unsigned short* Vt  = (unsigned short*)(ws + 16 * MB);  // 8 MB
  unsigned short* xb  = (unsigned short*)(ws + 24 * MB);  // 8 MB
  unsigned short* wqb = (unsigned short*)(ws + 32 * MB);  // 2 MB
  unsigned short* wkb = (unsigned short*)(ws + 34 * MB);  // 2 MB
  unsigned short* wvb = (unsigned short*)(ws + 36 * MB);  // 2 MB
  unsigned short* wob = (unsigned short*)(ws + 38 * MB);  // 2 MB -> 40 MB total

  // one-shot fp32 -> bf16 conversion (x + 4 weights)
  cvt_bf16<<<dim3(512, 8), 256, 0, stream>>>(x, Wq, Wk, Wv, Wo, xb, wqb, wkb, wvb, wob);
  // Q,K,V projections: 256x256-tile 8-wave deep-pipelined (T3+T4+T5)
  gemm_qkv<<<dim3(4, 16, 3), 512, 0, stream>>>(xb, wqb, wkb, wvb, Qf, Kf, Vt);
  // RoPE in place on Q,K (table-in-LDS; Q pre-scaled by 0.125)
  rope_inplace<<<dim3(MROWS), 256, 0, stream>>>(Qf, Kf, tpos);
  // causal attention; 512 paired blocks (uniform 33 trips), XCD-swizzled
  attn_kernel<<<dim3(512), 256, 0, stream>>>(Kf, Vt, Qf);
  // output projection (bf16 A, bf16 W, fp32 out)
  gemm_out<<<dim3(8, 32, 1), 256, 0, stream>>>(Qf, wob, out, MROWS, DMODEL, DMODEL);
}

// Round 9
// 197.204 us; speedup vs baseline: 1.0369x; 1.0369x over previous
//
#include <hip/hip_runtime.h>
#include <cstdint>
#include <cstddef>

#define SEQL   2048
#define DMODEL 1024
#define NHEADS 16
#define DHEAD  64
#define MROWS  4096   // BATCH * SEQ

typedef __attribute__((ext_vector_type(8))) short short8;   // 8 bf16 (4 VGPRs)
typedef __attribute__((ext_vector_type(4))) float f32x4;    // MFMA 16x16 C/D
typedef __attribute__((ext_vector_type(4))) unsigned int u32x4;

__device__ __forceinline__ unsigned short f2bf(float x) {
  unsigned int u = __float_as_uint(x);
  u += 0x7fffu + ((u >> 16) & 1u);   // round-to-nearest-even
  return (unsigned short)(u >> 16);
}
__device__ __forceinline__ float bf2f(unsigned short u) {
  return __uint_as_float(((unsigned int)u) << 16);
}
// pack two f32 -> 2xbf16 in one VGPR (RNE, same rounding as f2bf)
__device__ __forceinline__ unsigned int cvtpk(float lo, float hi) {
  unsigned int r;
  asm("v_cvt_pk_bf16_f32 %0, %1, %2" : "=v"(r) : "v"(lo), "v"(hi));
  return r;
}
// load 8 contiguous fp32, round to 8 bf16
__device__ __forceinline__ short8 cvt8(const float* __restrict__ p) {
  const float4 lo = *(const float4*)p;
  const float4 hi = *(const float4*)(p + 4);
  short8 v;
  v[0] = (short)f2bf(lo.x); v[1] = (short)f2bf(lo.y);
  v[2] = (short)f2bf(lo.z); v[3] = (short)f2bf(lo.w);
  v[4] = (short)f2bf(hi.x); v[5] = (short)f2bf(hi.y);
  v[6] = (short)f2bf(hi.z); v[7] = (short)f2bf(hi.w);
  return v;
}
// async global->LDS, 16B per lane; lds base must be wave-uniform
__device__ __forceinline__ void gload_lds16(const unsigned short* g, unsigned short* l) {
  __builtin_amdgcn_global_load_lds(
      (const __attribute__((address_space(1))) unsigned int*)g,
      (__attribute__((address_space(3))) unsigned int*)l, 16, 0, 0);
}

// ---------------------------------------------------------------------------
// One-shot fp32 -> bf16 conversion of x and the four weight matrices.
// ---------------------------------------------------------------------------
__global__ __launch_bounds__(256) void cvt_bf16(
    const float* __restrict__ x,  const float* __restrict__ wq,
    const float* __restrict__ wk, const float* __restrict__ wv,
    const float* __restrict__ wo,
    unsigned short* __restrict__ xb,  unsigned short* __restrict__ wqb,
    unsigned short* __restrict__ wkb, unsigned short* __restrict__ wvb,
    unsigned short* __restrict__ wob) {
  const int y = blockIdx.y;
  const float* src; unsigned short* dst;
  if (y < 4)       { src = x + ((size_t)y << 20); dst = xb + ((size_t)y << 20); }
  else if (y == 4) { src = wq; dst = wqb; }
  else if (y == 5) { src = wk; dst = wkb; }
  else if (y == 6) { src = wv; dst = wvb; }
  else             { src = wo; dst = wob; }
  const size_t i = ((size_t)blockIdx.x * 256 + threadIdx.x) * 8;
  *(short8*)(dst + i) = cvt8(src + i);
}

// ---------------------------------------------------------------------------
// QKV projection, all-bf16, async staging (m97-style) — PROVEN R17 version.
// z=0 -> Q bf16; z=1 -> K bf16; z=2 -> V transposed into Vt.
// (R18's 256x256 port was -5us: 192-block grid = 75% CU coverage; reverted.)
// ---------------------------------------------------------------------------
__global__ __launch_bounds__(256) void gemm_qkv(
    const unsigned short* __restrict__ A,
    const unsigned short* __restrict__ W0, const unsigned short* __restrict__ W1,
    const unsigned short* __restrict__ W2,
    unsigned short* __restrict__ C0, unsigned short* __restrict__ C1,
    unsigned short* __restrict__ Vt,
    int Mda, int Nda, int Kda) {
  const unsigned short* W;
  if (blockIdx.z == 0)      W = W0;
  else if (blockIdx.z == 1) W = W1;
  else                      W = W2;

  __shared__ __attribute__((aligned(16))) unsigned short As[128 * 32];
  __shared__ __attribute__((aligned(16))) unsigned short Bs[128 * 32];

  const int t = threadIdx.x;
  const int m0 = blockIdx.y * 128, n0 = blockIdx.x * 128;
  const int w = t >> 6, lane = t & 63;
  const int l15 = lane & 15, quad = lane >> 4;
  const int wm = (w >> 1) * 64, wn = (w & 1) * 64;

  const int r1 = t >> 2,         c1 = (t & 3) * 8;
  const int r2 = (t + 256) >> 2, c2 = (t & 3) * 8;
  unsigned short* asd1 = As + (size_t)(w << 6) * 8;
  unsigned short* asd2 = As + (size_t)(256 + (w << 6)) * 8;
  unsigned short* bsd1 = Bs + (size_t)(w << 6) * 8;
  unsigned short* bsd2 = Bs + (size_t)(256 + (w << 6)) * 8;

  f32x4 acc[4][4] = {};

  for (int k0 = 0; k0 < Kda; k0 += 32) {
    __syncthreads();
    gload_lds16(A + (size_t)(m0 + r1) * Kda + k0 + c1, asd1);
    gload_lds16(A + (size_t)(m0 + r2) * Kda + k0 + c2, asd2);
    gload_lds16(W + (size_t)(n0 + r1) * Kda + k0 + c1, bsd1);
    gload_lds16(W + (size_t)(n0 + r2) * Kda + k0 + c2, bsd2);
    __syncthreads();

    short8 af[4], bfr[4];
#pragma unroll
    for (int i = 0; i < 4; ++i)
      af[i] = *(const short8*)(&As[(wm + i * 16 + l15) * 32 + quad * 8]);
#pragma unroll
    for (int j = 0; j < 4; ++j)
      bfr[j] = *(const short8*)(&Bs[(wn + j * 16 + l15) * 32 + quad * 8]);
#pragma unroll
    for (int i = 0; i < 4; ++i)
#pragma unroll
      for (int j = 0; j < 4; ++j)
        acc[i][j] = __builtin_amdgcn_mfma_f32_16x16x32_bf16(af[i], bfr[j], acc[i][j], 0, 0, 0);
  }

  if (blockIdx.z != 2) {
    unsigned short* C = (blockIdx.z == 0) ? C0 : C1;
#pragma unroll
    for (int i = 0; i < 4; ++i)
#pragma unroll
      for (int j = 0; j < 4; ++j)
#pragma unroll
        for (int r = 0; r < 4; ++r) {
          int row = m0 + wm + i * 16 + quad * 4 + r;
          int col = n0 + wn + j * 16 + l15;
          C[(size_t)row * Nda + col] = f2bf(acc[i][j][r]);
        }
  } else {
    // V transposed write: 4 consecutive s-values per 8B store
#pragma unroll
    for (int i = 0; i < 4; ++i) {
      const int srow = m0 + wm + i * 16 + quad * 4;   // b*SEQL + s (s%4==0)
      const int bq = srow >> 11, s = srow & (SEQL - 1);
#pragma unroll
      for (int j = 0; j < 4; ++j) {
        const int col = n0 + wn + j * 16 + l15;       // h*64 + d
        ushort4 v;
        v.x = f2bf(acc[i][j][0]); v.y = f2bf(acc[i][j][1]);
        v.z = f2bf(acc[i][j][2]); v.w = f2bf(acc[i][j][3]);
        *(ushort4*)(Vt + ((size_t)(bq * DMODEL + col)) * SEQL + s) = v;
      }
    }
  }
}

// ---------------------------------------------------------------------------
// Output projection: A bf16 [M][K], W bf16 [N][K], C fp32 [M][N]
// ---------------------------------------------------------------------------
__global__ __launch_bounds__(256) void gemm_out(
    const unsigned short* __restrict__ A,
    const unsigned short* __restrict__ W,
    float* __restrict__ C,
    int Mda, int Nda, int Kda) {
  __shared__ __attribute__((aligned(16))) unsigned short As[128 * 32];
  __shared__ __attribute__((aligned(16))) unsigned short Bs[128 * 32];

  const int t = threadIdx.x;
  const int m0 = blockIdx.y * 128, n0 = blockIdx.x * 128;
  const int w = t >> 6, lane = t & 63;
  const int l15 = lane & 15, quad = lane >> 4;
  const int wm = (w >> 1) * 64, wn = (w & 1) * 64;

  const int r1 = t >> 2,         c1 = (t & 3) * 8;
  const int r2 = (t + 256) >> 2, c2 = (t & 3) * 8;
  unsigned short* asd1 = As + (size_t)(w << 6) * 8;
  unsigned short* asd2 = As + (size_t)(256 + (w << 6)) * 8;
  unsigned short* bsd1 = Bs + (size_t)(w << 6) * 8;
  unsigned short* bsd2 = Bs + (size_t)(256 + (w << 6)) * 8;

  f32x4 acc[4][4] = {};

  for (int k0 = 0; k0 < Kda; k0 += 32) {
    __syncthreads();
    gload_lds16(A + (size_t)(m0 + r1) * Kda + k0 + c1, asd1);
    gload_lds16(A + (size_t)(m0 + r2) * Kda + k0 + c2, asd2);
    gload_lds16(W + (size_t)(n0 + r1) * Kda + k0 + c1, bsd1);
    gload_lds16(W + (size_t)(n0 + r2) * Kda + k0 + c2, bsd2);
    __syncthreads();

    short8 af[4], bfr[4];
#pragma unroll
    for (int i = 0; i < 4; ++i)
      af[i] = *(const short8*)(&As[(wm + i * 16 + l15) * 32 + quad * 8]);
#pragma unroll
    for (int j = 0; j < 4; ++j)
      bfr[j] = *(const short8*)(&Bs[(wn + j * 16 + l15) * 32 + quad * 8]);
#pragma unroll
    for (int i = 0; i < 4; ++i)
#pragma unroll
      for (int j = 0; j < 4; ++j)
        acc[i][j] = __builtin_amdgcn_mfma_f32_16x16x32_bf16(af[i], bfr[j], acc[i][j], 0, 0, 0);
  }

#pragma unroll
  for (int i = 0; i < 4; ++i)
#pragma unroll
    for (int j = 0; j < 4; ++j)
#pragma unroll
      for (int r = 0; r < 4; ++r) {
        int row = m0 + wm + i * 16 + quad * 4 + r;
        int col = n0 + wn + j * 16 + l15;
        C[(size_t)row * Nda + col] = acc[i][j][r];
      }
}

// ---------------------------------------------------------------------------
// In-place RoPE on bf16 Q and K flat [M][1024].  Table-in-LDS (R17).
// ---------------------------------------------------------------------------
__global__ __launch_bounds__(256) void rope_inplace(unsigned short* __restrict__ Q,
                                                    unsigned short* __restrict__ K,
                                                    const int* __restrict__ pos_arr) {
  __shared__ float cs[32], sn[32];
  const int row = blockIdx.x;            // b*SEQ + s
  const int s = row & (SEQL - 1);
  const int t = threadIdx.x;
  if (t < 32) {
    const float pos = (float)pos_arr[s];
    // log2(10000)/32 = 0.4152410118609203
    const float inv = exp2f((float)t * -0.4152410118609203f);
    const float ang = pos * inv;
    float ss, cc;
    sincosf(ang, &ss, &cc);
    cs[t] = cc; sn[t] = ss;
  }
  __syncthreads();

  // thread t handles head h = t>>4, pairs i0 = (t&15)*2 and i0+1 (4 shorts)
  const int i0 = (t & 15) * 2;
  const size_t base = (size_t)row * DMODEL + (size_t)(t >> 4) * DHEAD + (size_t)i0 * 2;
  const float c0 = cs[i0], s0 = sn[i0];
  const float c1 = cs[i0 + 1], s1 = sn[i0 + 1];

  ushort4 q = *(const ushort4*)(Q + base);
  ushort4 k = *(const ushort4*)(K + base);
  ushort4 r;
  float e, o;
  e = bf2f(q.x); o = bf2f(q.y);
  r.x = f2bf((e * c0 - o * s0) * 0.125f);
  r.y = f2bf((e * s0 + o * c0) * 0.125f);
  e = bf2f(q.z); o = bf2f(q.w);
  r.z = f2bf((e * c1 - o * s1) * 0.125f);
  r.w = f2bf((e * s1 + o * c1) * 0.125f);
  *(ushort4*)(Q + base) = r;

  e = bf2f(k.x); o = bf2f(k.y);
  r.x = f2bf(e * c0 - o * s0);
  r.y = f2bf(e * s0 + o * c0);
  e = bf2f(k.z); o = bf2f(k.w);
  r.z = f2bf(e * c1 - o * s1);
  r.w = f2bf(e * s1 + o * c1);
  *(ushort4*)(K + base) = r;
}

// ---------------------------------------------------------------------------
// Causal attention — R0 structure + R19 serial-chain VALU diet:
//  (a) P-pack via v_cvt_pk_bf16_f32 (8 cvtpk replace 16x 4-op f2bf packs;
//      identical RNE bits).
//  (b) lp via MFMA: lpacc = mfma(ones, bp, lpacc) sums P rows in the matrix
//      pipe (2 MFMA/trip replace 16 dependent VALU adds/trip) AND already
//      reduces over quads (k-dim), deleting the final shfl_xor pair.
//      il = 1/lpacc[0] (all rows of the ones-product identical, col=q=l15).
// Everything else is the proven R0 kernel (46.8us, VGPR 44, no spills).
// ---------------------------------------------------------------------------
__global__ __launch_bounds__(256, 2) void attn_kernel(const unsigned short* __restrict__ Kf,
                                                      const unsigned short* __restrict__ Vt,
                                                      unsigned short* __restrict__ Qio) {
  __shared__ __attribute__((aligned(16))) unsigned short Ks[4096];  // 8 KB: kv64 x d64
  __shared__ __attribute__((aligned(16))) unsigned short Vs[4096];  // 8 KB: d64 x kv64

  const int id = blockIdx.x;                    // id = grp*128 + qpair*8 + xcd
  const int bh = ((id >> 7) << 3) | (id & 7);   // grp*8 + xcd (L2 locality)
  const int qpair = (id >> 3) & 15;             // 0..15
  const int b = bh >> 4, h = bh & 15;
  const int w = threadIdx.x >> 6;
  const int lane = threadIdx.x & 63;
  const int l15 = lane & 15, quad = lane >> 4;

  // staging source addresses (lane-permuted so LDS slot = fragment layout)
  const int g = (w << 6) | lane;
  const int ktau = g >> 7, kseg = (g >> 4) & 7, km = g & 15;
  const int kvl = 8 * (km >> 2) + (km & 3) + 4 * ktau;
  const unsigned short* kstage = Kf + ((size_t)(b * SEQL + kvl)) * DMODEL + h * DHEAD + kseg * 8;
  const int vdb = (g >> 6) & 3, vq = (g >> 4) & 3, vm = g & 15;
  const unsigned short* vstage = Vt + ((size_t)(bh * DHEAD + vdb * 16 + vm)) * SEQL + vq * 8;
  unsigned short* kdst0 = Ks + (size_t)(w << 6) * 8;          // kv 0..31 half
  unsigned short* kdst1 = Ks + 2048 + (size_t)(w << 6) * 8;   // kv 32..63 half
  unsigned short* vdst0 = Vs + (size_t)(w << 6) * 8;
  unsigned short* vdst1 = Vs + 2048 + (size_t)(w << 6) * 8;

  // fragment read offset (shorts) within a 2048-short half
  const int rs = (l15 + (quad << 4)) << 3;

  // all-ones bf16 A-fragment for the lp row-sum MFMA
  const short8 ones = {(short)0x3F80, (short)0x3F80, (short)0x3F80, (short)0x3F80,
                       (short)0x3F80, (short)0x3F80, (short)0x3F80, (short)0x3F80};

#pragma unroll 1
  for (int phase = 0; phase < 2; ++phase) {
    const int qblk = (phase == 0) ? qpair : 31 - qpair;
    const int qw = qblk * 64 + w * 16;
    const int qrow = qw + l15;

    // Q B-frag: n=l15 (q), k=8*quad+j (d)
    const unsigned short* qp = Qio + ((size_t)(b * SEQL + qrow)) * DMODEL + h * DHEAD + quad * 8;
    const short8 bq0 = *(const short8*)(qp);
    const short8 bq1 = *(const short8*)(qp + 32);

    f32x4 oa0 = {0.f, 0.f, 0.f, 0.f}, oa1 = oa0, oa2 = oa0, oa3 = oa0;
    f32x4 lpacc = oa0;

    const int trips = qblk + 1;   // kv64 tiles; block-uniform
    for (int t = 0; t < trips; ++t) {
      const int kv0 = t * 64;
      __syncthreads();   // all waves done reading previous tile
      gload_lds16(kstage + (size_t)kv0 * DMODEL, kdst0);
      gload_lds16(kstage + (size_t)(kv0 + 32) * DMODEL, kdst1);
      gload_lds16(vstage + kv0, vdst0);
      gload_lds16(vstage + kv0 + 32, vdst1);
      __syncthreads();   // staged data visible

      // QK^T: 4 score accumulators (kv groups +0, +4, +32, +36)
      const short8 ak10 = *(const short8*)(Ks + rs);
      const short8 ak11 = *(const short8*)(Ks + rs + 512);
      const short8 ak20 = *(const short8*)(Ks + rs + 1024);
      const short8 ak21 = *(const short8*)(Ks + rs + 1536);
      const short8 ak30 = *(const short8*)(Ks + 2048 + rs);
      const short8 ak31 = *(const short8*)(Ks + 2048 + rs + 512);
      const short8 ak40 = *(const short8*)(Ks + 2048 + rs + 1024);
      const short8 ak41 = *(const short8*)(Ks + 2048 + rs + 1536);
      f32x4 z = {0.f, 0.f, 0.f, 0.f};
      f32x4 s1 = __builtin_amdgcn_mfma_f32_16x16x32_bf16(ak10, bq0, z, 0, 0, 0);
      s1 = __builtin_amdgcn_mfma_f32_16x16x32_bf16(ak11, bq1, s1, 0, 0, 0);
      f32x4 s2 = __builtin_amdgcn_mfma_f32_16x16x32_bf16(ak20, bq0, z, 0, 0, 0);
      s2 = __builtin_amdgcn_mfma_f32_16x16x32_bf16(ak21, bq1, s2, 0, 0, 0);
      f32x4 s3 = __builtin_amdgcn_mfma_f32_16x16x32_bf16(ak30, bq0, z, 0, 0, 0);
      s3 = __builtin_amdgcn_mfma_f32_16x16x32_bf16(ak31, bq1, s3, 0, 0, 0);
      f32x4 s4 = __builtin_amdgcn_mfma_f32_16x16x32_bf16(ak40, bq0, z, 0, 0, 0);
      s4 = __builtin_amdgcn_mfma_f32_16x16x32_bf16(ak41, bq1, s4, 0, 0, 0);

      // exp (+causal mask on the straddle trip) -> PV B-operands via cvtpk
      short8 bp0, bp1;
      if (kv0 + 63 <= qw) {   // wave-uniform fast path: no masking needed
        const float p10 = __expf(s1[0]), p11 = __expf(s1[1]);
        const float p12 = __expf(s1[2]), p13 = __expf(s1[3]);
        const float p20 = __expf(s2[0]), p21 = __expf(s2[1]);
        const float p22 = __expf(s2[2]), p23 = __expf(s2[3]);
        const float p30 = __expf(s3[0]), p31 = __expf(s3[1]);
        const float p32 = __expf(s3[2]), p33 = __expf(s3[3]);
        const float p40 = __expf(s4[0]), p41 = __expf(s4[1]);
        const float p42 = __expf(s4[2]), p43 = __expf(s4[3]);
        u32x4 lo, hi;
        lo[0] = cvtpk(p10, p11); lo[1] = cvtpk(p12, p13);
        lo[2] = cvtpk(p20, p21); lo[3] = cvtpk(p22, p23);
        hi[0] = cvtpk(p30, p31); hi[1] = cvtpk(p32, p33);
        hi[2] = cvtpk(p40, p41); hi[3] = cvtpk(p42, p43);
        bp0 = __builtin_bit_cast(short8, lo);
        bp1 = __builtin_bit_cast(short8, hi);
      } else {
        float p1[4], p2[4], p3[4], p4[4];
#pragma unroll
        for (int r = 0; r < 4; ++r) {
          const int kv1 = kv0 + 8 * quad + r;
          p1[r] = (kv1 > qrow)      ? 0.f : __expf(s1[r]);
          p2[r] = (kv1 + 4 > qrow)  ? 0.f : __expf(s2[r]);
          p3[r] = (kv1 + 32 > qrow) ? 0.f : __expf(s3[r]);
          p4[r] = (kv1 + 36 > qrow) ? 0.f : __expf(s4[r]);
        }
        u32x4 lo, hi;
        lo[0] = cvtpk(p1[0], p1[1]); lo[1] = cvtpk(p1[2], p1[3]);
        lo[2] = cvtpk(p2[0], p2[1]); lo[3] = cvtpk(p2[2], p2[3]);
        hi[0] = cvtpk(p3[0], p3[1]); hi[1] = cvtpk(p3[2], p3[3]);
        hi[2] = cvtpk(p4[0], p4[1]); hi[3] = cvtpk(p4[2], p4[3]);
        bp0 = __builtin_bit_cast(short8, lo);
        bp1 = __builtin_bit_cast(short8, hi);
      }

      // lp row-sum in the matrix pipe: D[row,q] = sum_k 1 * P[k,q]
      lpacc = __builtin_amdgcn_mfma_f32_16x16x32_bf16(ones, bp0, lpacc, 0, 0, 0);
      lpacc = __builtin_amdgcn_mfma_f32_16x16x32_bf16(ones, bp1, lpacc, 0, 0, 0);

      // PV: A = V^T frags (d-block x kv-half), B = bp
      const short8 av0l = *(const short8*)(Vs + rs);
      const short8 av1l = *(const short8*)(Vs + rs + 512);
      const short8 av2l = *(const short8*)(Vs + rs + 1024);
      const short8 av3l = *(const short8*)(Vs + rs + 1536);
      const short8 av0h = *(const short8*)(Vs + 2048 + rs);
      const short8 av1h = *(const short8*)(Vs + 2048 + rs + 512);
      const short8 av2h = *(const short8*)(Vs + 2048 + rs + 1024);
      const short8 av3h = *(const short8*)(Vs + 2048 + rs + 1536);
      oa0 = __builtin_amdgcn_mfma_f32_16x16x32_bf16(av0l, bp0, oa0, 0, 0, 0);
      oa1 = __builtin_amdgcn_mfma_f32_16x16x32_bf16(av1l, bp0, oa1, 0, 0, 0);
      oa2 = __builtin_amdgcn_mfma_f32_16x16x32_bf16(av2l, bp0, oa2, 0, 0, 0);
      oa3 = __builtin_amdgcn_mfma_f32_16x16x32_bf16(av3l, bp0, oa3, 0, 0, 0);
      oa0 = __builtin_amdgcn_mfma_f32_16x16x32_bf16(av0h, bp1, oa0, 0, 0, 0);
      oa1 = __builtin_amdgcn_mfma_f32_16x16x32_bf16(av1h, bp1, oa1, 0, 0, 0);
      oa2 = __builtin_amdgcn_mfma_f32_16x16x32_bf16(av2h, bp1, oa2, 0, 0, 0);
      oa3 = __builtin_amdgcn_mfma_f32_16x16x32_bf16(av3h, bp1, oa3, 0, 0, 0);
    }

    // lpacc[0] holds sum_kv P[q=l15] (all rows identical; k-reduction done
    // inside the MFMA, so no cross-quad shuffle needed)
    const float il = 1.f / lpacc[0];

    // O^T: lane holds q=l15's d = db*16 + 4*quad + r  -> 4x ushort4 stores
    unsigned short* ob = Qio + ((size_t)(b * SEQL + qrow)) * DMODEL + h * DHEAD + quad * 4;
    {
      ushort4 v;
      v.x = f2bf(oa0[0] * il); v.y = f2bf(oa0[1] * il);
      v.z = f2bf(oa0[2] * il); v.w = f2bf(oa0[3] * il);
      *(ushort4*)(ob) = v;
      v.x = f2bf(oa1[0] * il); v.y = f2bf(oa1[1] * il);
      v.z = f2bf(oa1[2] * il); v.w = f2bf(oa1[3] * il);
      *(ushort4*)(ob + 16) = v;
      v.x = f2bf(oa2[0] * il); v.y = f2bf(oa2[1] * il);
      v.z = f2bf(oa2[2] * il); v.w = f2bf(oa2[3] * il);
      *(ushort4*)(ob + 32) = v;
      v.x = f2bf(oa3[0] * il); v.y = f2bf(oa3[1] * il);
      v.z = f2bf(oa3[2] * il); v.w = f2bf(oa3[3] * il);
      *(ushort4*)(ob + 48) = v;
    }
  }
}

// ---------------------------------------------------------------------------
extern "C" void kernel_launch(void* const* d_in, const int* in_sizes, int n_in,
                              void* d_out, int out_size, void* d_ws, size_t ws_size,
                              hipStream_t stream) {
  (void)in_sizes; (void)n_in; (void)out_size; (void)ws_size;
  const float* x  = (const float*)d_in[0];
  const int* tpos = (const int*)d_in[1];
  const float* Wq = (const float*)d_in[2];
  const float* Wk = (const float*)d_in[3];
  const float* Wv = (const float*)d_in[4];
  const float* Wo = (const float*)d_in[5];
  float* out      = (float*)d_out;

  char* ws = (char*)d_ws;
  const size_t MB = 1024 * 1024;
  unsigned short* Qf  = (unsigned short*)(ws);            // 8 MB
  unsigned short* Kf  = (unsigned short*)(ws + 8 * MB);   // 8 MB
  unsigned short* Vt  = (unsigned short*)(ws + 16 * MB);  // 8 MB
  unsigned short* xb  = (unsigned short*)(ws + 24 * MB);  // 8 MB
  unsigned short* wqb = (unsigned short*)(ws + 32 * MB);  // 2 MB
  unsigned short* wkb = (unsigned short*)(ws + 34 * MB);  // 2 MB
  unsigned short* wvb = (unsigned short*)(ws + 36 * MB);  // 2 MB
  unsigned short* wob = (unsigned short*)(ws + 38 * MB);  // 2 MB -> 40 MB total

  // one-shot fp32 -> bf16 conversion (x + 4 weights)
  cvt_bf16<<<dim3(512, 8), 256, 0, stream>>>(x, Wq, Wk, Wv, Wo, xb, wqb, wkb, wvb, wob);
  // Q,K,V projections (all-bf16, async staging; V written transposed)
  gemm_qkv<<<dim3(8, 32, 3), 256, 0, stream>>>(xb, wqb, wkb, wvb, Qf, Kf, Vt, MROWS, DMODEL, DMODEL);
  // RoPE in place on Q,K (table-in-LDS; Q pre-scaled by 0.125)
  rope_inplace<<<dim3(MROWS), 256, 0, stream>>>(Qf, Kf, tpos);
  // causal attention; 512 paired blocks (uniform 33 trips), XCD-swizzled
  attn_kernel<<<dim3(512), 256, 0, stream>>>(Kf, Vt, Qf);
  // output projection (bf16 A, bf16 W, fp32 out)
  gemm_out<<<dim3(8, 32, 1), 256, 0, stream>>>(Qf, wob, out, MROWS, DMODEL, DMODEL);
}